// Round 3
// baseline (141.336 us; speedup 1.0000x reference)
//
#include <hip/hip_runtime.h>

#define SEQ 79
#define DM 1024
#define BATCHN 512
#define LP 81            // LDS pitch: stride 81 mod 32 = 17 (odd) -> conflict-free k-strides
#define NPB (SEQ * SEQ)  // 6241 pairs per batch

__device__ __forceinline__ float gelu_fast(float a) {
    // 0.5*a*(1+tanh(0.79788456*(a+0.044715*a^3))) = a - a/(exp2(c1*a+c2*a^3)+1)
    const float c1 = 2.3022585093f;   // 2*0.7978845608*log2(e)
    const float c2 = 0.1029450750f;   // c1*0.044715
    const float t  = a * fmaf(a * a, c2, c1);
    const float e  = __builtin_amdgcn_exp2f(t);
    const float r  = __builtin_amdgcn_rcpf(e + 1.0f);
    return fmaf(-a, r, a);
}

// One block per batch. Phase 1: 4 waves compute u'[32], v'[32], color for the
// 79 tokens into LDS (k1's algorithm). Phase 2: 256 threads sweep the 6241
// pairs reading operands from LDS; coalesced stores to the transposed output.
__global__ __launch_bounds__(256, 2) void fused_bias(
    const float* __restrict__ x,
    const float* __restrict__ piece_w, const float* __restrict__ piece_b,
    const float* __restrict__ color_w, const float* __restrict__ color_b,
    const float* __restrict__ mlp1_w,  const float* __restrict__ mlp1_b,
    const float* __restrict__ mlp2_w,  const float* __restrict__ mlp2_b,
    float* __restrict__ out)
{
    __shared__ float uS[32 * LP];
    __shared__ float vS[32 * LP];
    __shared__ float colS[SEQ];

    const int tid  = threadIdx.x;
    const int lane = tid & 63;
    const int wv   = tid >> 6;          // wave id 0..3
    const int b    = blockIdx.x;
    const int k    = lane & 31;
    const bool is_u = (lane < 32);

    // ---- one-time: per-lane projection weights (channels c = q*256+lane*4+t)
    float wp[4][4][7];
#pragma unroll
    for (int q = 0; q < 4; ++q)
#pragma unroll
        for (int t = 0; t < 4; ++t) {
            const int c = q * 256 + lane * 4 + t;
#pragma unroll
            for (int e = 0; e < 6; ++e) wp[q][t][e] = piece_w[c * 6 + e];
            wp[q][t][6] = color_w[c];
        }

    // per-lane u'/v' combination weights
    float wsp0 = mlp1_w[0 * 32 + k];
    float wsp1 = mlp1_w[1 * 32 + k];
    if (!is_u) { wsp0 = -wsp0; wsp1 = -wsp1; }
    const float bias1 = is_u ? mlp1_b[k] : 0.0f;
    float wc[6];
#pragma unroll
    for (int c = 0; c < 6; ++c)
        wc[c] = mlp1_w[((is_u ? 2 : 8) + c) * 32 + k];

    float pb[6];
#pragma unroll
    for (int e = 0; e < 6; ++e) pb[e] = piece_b[e];
    const float cb = color_b[0];

    // ---------------- Phase 1: 79 token rows -> LDS ----------------
#pragma unroll 2
    for (int n = wv; n < SEQ; n += 4) {
        const float4* xr = (const float4*)(x + ((size_t)b * SEQ + n) * DM);
        float4 xv[4];
#pragma unroll
        for (int q = 0; q < 4; ++q) xv[q] = xr[q * 64 + lane];

        float acc[7] = {0.f, 0.f, 0.f, 0.f, 0.f, 0.f, 0.f};
#pragma unroll
        for (int q = 0; q < 4; ++q) {
            const float xs[4] = {xv[q].x, xv[q].y, xv[q].z, xv[q].w};
#pragma unroll
            for (int t = 0; t < 4; ++t)
#pragma unroll
                for (int e = 0; e < 7; ++e)
                    acc[e] = fmaf(xs[t], wp[q][t][e], acc[e]);
        }

        // butterfly reduce across the full wave
#pragma unroll
        for (int e = 0; e < 7; ++e) {
#pragma unroll
            for (int m = 32; m >= 1; m >>= 1)
                acc[e] += __shfl_xor(acc[e], m, 64);
        }

        float p[6];
#pragma unroll
        for (int e = 0; e < 6; ++e) p[e] = acc[e] + pb[e];

        const float fx = (n < 64) ? (float)(n >> 3) : 0.0f;
        const float fy = (n < 64) ? (float)(n & 7) : 0.0f;

        float val = bias1;
        val = fmaf(fx, wsp0, val);
        val = fmaf(fy, wsp1, val);
#pragma unroll
        for (int c = 0; c < 6; ++c) val = fmaf(p[c], wc[c], val);

        float* dst = is_u ? uS : vS;            // cndmask'd base -> 1 ds_write
        dst[k * LP + n] = val;
        if (lane == 0) colS[n] = acc[6] + cb;
    }

    __syncthreads();

    // ---------------- Phase 2: 6241 pairs from LDS ----------------
    const size_t ob = (size_t)b * (8 * NPB);
    for (int p = tid; p < NPB; p += 256) {
        const unsigned i = (unsigned)p / 79u;
        const unsigned j = (unsigned)p - i * 79u;

        const float same = (colS[i] == colS[j]) ? 1.0f : 0.0f;

        float acc2[8] = {0.f, 0.f, 0.f, 0.f, 0.f, 0.f, 0.f, 0.f};
#pragma unroll
        for (int kk = 0; kk < 32; ++kk) {
            float a = uS[kk * LP + i] + vS[kk * LP + j];
            a = fmaf(same, mlp1_w[14 * 32 + kk], a);      // uniform -> s_load
            const float h = gelu_fast(a);
#pragma unroll
            for (int e = 0; e < 8; ++e)
                acc2[e] = fmaf(h, mlp2_w[kk * 8 + e], acc2[e]);  // uniform -> s_load
        }

#pragma unroll
        for (int e = 0; e < 8; ++e)
            out[ob + (size_t)e * NPB + p] = acc2[e] + mlp2_b[e];
    }
}

extern "C" void kernel_launch(void* const* d_in, const int* in_sizes, int n_in,
                              void* d_out, int out_size, void* d_ws, size_t ws_size,
                              hipStream_t stream) {
    const float* x       = (const float*)d_in[0];
    const float* piece_w = (const float*)d_in[1];
    const float* piece_b = (const float*)d_in[2];
    const float* color_w = (const float*)d_in[3];
    const float* color_b = (const float*)d_in[4];
    const float* mlp1_w  = (const float*)d_in[5];
    const float* mlp1_b  = (const float*)d_in[6];
    const float* mlp2_w  = (const float*)d_in[7];
    const float* mlp2_b  = (const float*)d_in[8];
    float* out = (float*)d_out;

    hipLaunchKernelGGL(fused_bias, dim3(BATCHN), dim3(256), 0, stream,
                       x, piece_w, piece_b, color_w, color_b,
                       mlp1_w, mlp1_b, mlp2_w, mlp2_b, out);
}